// Round 3
// baseline (1207.314 us; speedup 1.0000x reference)
//
#include <hip/hip_runtime.h>
#include <hip/hip_bf16.h>
#include <cstdint>

// Problem constants
constexpr int Bb = 8, Cc = 256, Hh = 64, Ww = 64, Nn = 4096;
constexpr int KD = 128, VD = 256, HP = 66; // HP = padded spatial (64+2)

typedef __attribute__((ext_vector_type(8))) short short8_t;   // 8 bf16 (4 VGPR) MFMA frag
typedef __attribute__((ext_vector_type(4))) short shortx4;    // 4 bf16 packed store
typedef __attribute__((ext_vector_type(4))) float floatx4;    // MFMA accumulator

static __device__ __forceinline__ ushort f2bf(float f) {
    union { float f; uint32_t u; } v{f};
    uint32_t r = v.u + 0x7FFFu + ((v.u >> 16) & 1u);  // RNE
    return (ushort)(r >> 16);
}
static __device__ __forceinline__ float bf2f(ushort b) {
    union { uint32_t u; float f; } v{(uint32_t)b << 16};
    return v.f;
}

// ---------------------------------------------------------------------------
// K1: x[b][c][y][x] (f32) -> xpad[b][y+1][x+1][c] (bf16, channel-last).
// Borders were zeroed by hipMemsetAsync. LDS transpose for coalescing.
__global__ __launch_bounds__(256) void pad_transpose(const float* __restrict__ x,
                                                     ushort* __restrict__ xpad) {
    int y = blockIdx.x, b = blockIdx.y, cg = blockIdx.z;   // cg: 64-channel group
    int t = threadIdx.x;
    __shared__ float tile[64][65];
    int xcol = t & 63;
    int crow = t >> 6;  // 0..3
    const float* xb = x + ((size_t)(b * Cc + cg * 64) * Nn) + y * 64;
#pragma unroll
    for (int i = 0; i < 16; i++) {
        int c = crow + i * 4;
        tile[c][xcol] = xb[(size_t)c * Nn + xcol];
    }
    __syncthreads();
    int c = t & 63;
    int x4 = t >> 6;
    ushort* dst = xpad + (((size_t)(b * HP + (y + 1)) * HP) + 1) * Cc + cg * 64 + c;
#pragma unroll
    for (int i = 0; i < 16; i++) {
        int xx = x4 + i * 4;
        dst[(size_t)xx * Cc] = f2bf(tile[c][xx]);
    }
}

// ---------------------------------------------------------------------------
// K2: repack weights w[oc][c][3][3] (f32) -> wt[r][oc][c] (bf16), r = dy*3+dx
__global__ __launch_bounds__(256) void repack_w(const float* __restrict__ kw,
                                                const float* __restrict__ vw,
                                                ushort* __restrict__ wtk,
                                                ushort* __restrict__ wtv) {
    int idx = blockIdx.x * 256 + threadIdx.x;
    const int nk = KD * Cc;   // 32768
    const int nv = VD * Cc;   // 65536
    if (idx < nk) {
        const float* src = kw + (size_t)idx * 9;
        int oc = idx / Cc, c = idx % Cc;
#pragma unroll
        for (int r = 0; r < 9; r++) wtk[((size_t)r * KD + oc) * Cc + c] = f2bf(src[r]);
    } else if (idx < nk + nv) {
        int j = idx - nk;
        const float* src = vw + (size_t)j * 9;
        int oc = j / Cc, c = j % Cc;
#pragma unroll
        for (int r = 0; r < 9; r++) wtv[((size_t)r * VD + oc) * Cc + c] = f2bf(src[r]);
    }
}

// ---------------------------------------------------------------------------
// K3: implicit-GEMM conv3x3 via MFMA. Block = 4 waves, M_tile=128 oc,
// N_tile=64 (one image row), K = 9 taps x 256 ch. Each wave owns 16 columns.
// MODE 0: key conv -> Kt[b][pos][oc] bf16 (+bias).
// MODE 1: val conv -> d_out ch 0..255 as FLOAT32 (+bias) and Vb bf16 copy.
template <int MODE, int OC>
__global__ __launch_bounds__(256) void conv_gemm(const ushort* __restrict__ xpad,
                                                 const ushort* __restrict__ wt,
                                                 const float* __restrict__ bias,
                                                 ushort* __restrict__ kt_out,
                                                 float* __restrict__ f32_out,
                                                 ushort* __restrict__ vb_out) {
    int y = blockIdx.x, b = blockIdx.y, ocg = blockIdx.z;
    int lane = threadIdx.x & 63, wv = threadIdx.x >> 6;
    int l15 = lane & 15, g = lane >> 4;
    int oc0 = ocg * 128;

    floatx4 acc[8];
#pragma unroll
    for (int m = 0; m < 8; m++) acc[m] = (floatx4){0.f, 0.f, 0.f, 0.f};

    const ushort* xb = xpad + ((size_t)b * HP * HP) * Cc;
    int xcol = wv * 16 + l15;  // output x position (wave's 16 columns)

#pragma unroll 1
    for (int r = 0; r < 9; r++) {
        int dy = r / 3, dx = r % 3;
        const ushort* bsrc = xb + ((size_t)(y + dy) * HP + xcol + dx) * Cc + g * 8;
        const ushort* asrc = wt + ((size_t)r * OC + oc0 + l15) * Cc + g * 8;
#pragma unroll
        for (int cc = 0; cc < 8; cc++) {  // 8 k-steps of 32 channels
            short8_t bfrag = *(const short8_t*)(bsrc + cc * 32);
#pragma unroll
            for (int m = 0; m < 8; m++) {
                short8_t afrag = *(const short8_t*)(asrc + (size_t)m * 16 * Cc + cc * 32);
                acc[m] = __builtin_amdgcn_mfma_f32_16x16x32_bf16(afrag, bfrag, acc[m], 0, 0, 0);
            }
        }
    }

    int pos = y * 64 + xcol;
    if (MODE == 0) {
        // Kt[b][pos][oc]; D rows (oc) = m*16 + g*4 + reg -> 4 consecutive, pack 8B
        ushort* kt = kt_out + ((size_t)(b * Nn + pos)) * KD;
#pragma unroll
        for (int m = 0; m < 8; m++) {
            floatx4 bv = *(const floatx4*)(bias + m * 16 + g * 4);
            shortx4 pk;
#pragma unroll
            for (int r = 0; r < 4; r++) pk[r] = (short)f2bf(acc[m][r] + bv[r]);
            *(shortx4*)(kt + m * 16 + g * 4) = pk;
        }
    } else {
#pragma unroll
        for (int m = 0; m < 8; m++) {
            floatx4 bv = *(const floatx4*)(bias + oc0 + m * 16 + g * 4);
#pragma unroll
            for (int r = 0; r < 4; r++) {
                int oc = oc0 + m * 16 + g * 4 + r;
                float v = acc[m][r] + bv[r];
                f32_out[((size_t)(b * 512 + oc)) * Nn + pos] = v;       // d_out f32
                vb_out[((size_t)(b * VD + oc)) * Nn + pos] = f2bf(v);   // bf16 for PV MFMA
            }
        }
    }
}

// ---------------------------------------------------------------------------
// K4: sq[b*N+pos] = sum_ch Kt[pos][ch]^2 (f32, from the bf16 Kt so that the
// diagonal of S is exactly 0).
__global__ __launch_bounds__(256) void sq_kernel(const ushort* __restrict__ kt,
                                                 float* __restrict__ sq) {
    int idx = blockIdx.x * 256 + threadIdx.x;  // b*N + pos, 32768 total
    const ushort* src = kt + (size_t)idx * KD;
    float s = 0.f;
#pragma unroll
    for (int i = 0; i < 16; i++) {
        short8_t v = *(const short8_t*)(src + i * 8);
#pragma unroll
        for (int e = 0; e < 8; e++) {
            float f = bf2f((ushort)v[e]);
            s += f * f;
        }
    }
    sq[idx] = s;
}

// ---------------------------------------------------------------------------
// K5: fused attention. Block = 4 waves, each wave owns 16 columns j of a
// 64-column tile. Loop over 64-row i-tiles: S = Kt_i . Kt_j (MFMA over 128ch),
// P = exp2(scale*(2S - sq_i - sq_j))  (softmax max is exactly 0), transpose P
// through per-wave LDS (barrier-protected), PV MFMA into 256-dim acc reading
// Vb (bf16), normalize by column sum, write d_out channels 256..511 as f32.
__global__ __launch_bounds__(256) void attn_kernel(const ushort* __restrict__ kt,
                                                   const ushort* __restrict__ vb,
                                                   const float* __restrict__ sq,
                                                   float* __restrict__ out) {
    int jt = blockIdx.x, b = blockIdx.y;
    int lane = threadIdx.x & 63, wv = threadIdx.x >> 6;
    int l15 = lane & 15, g = lane >> 4;

    __shared__ ushort pt[4][16][72];  // per-wave P^T tile [j][i], padded row

    int j = jt * 64 + wv * 16 + l15;
    const ushort* ktb = kt + ((size_t)b * Nn) * KD;
    const ushort* vbb = vb + ((size_t)b * VD) * Nn;
    const float* sqb = sq + b * Nn;

    float sqj = sqb[j];
    short8_t kj[4];
#pragma unroll
    for (int kk = 0; kk < 4; kk++)
        kj[kk] = *(const short8_t*)(ktb + (size_t)j * KD + kk * 32 + g * 8);

    floatx4 acc[16];
#pragma unroll
    for (int m = 0; m < 16; m++) acc[m] = (floatx4){0.f, 0.f, 0.f, 0.f};
    float dsum = 0.f;
    constexpr float kScale = 0.08838834764831845f * 1.4426950408889634f;  // log2e/sqrt(128)

#pragma unroll 1
    for (int it = 0; it < 64; ++it) {
        int i0 = it * 64;
        floatx4 sacc[4];
#pragma unroll
        for (int f = 0; f < 4; f++) sacc[f] = (floatx4){0.f, 0.f, 0.f, 0.f};
#pragma unroll
        for (int kk = 0; kk < 4; kk++) {
#pragma unroll
            for (int f = 0; f < 4; f++) {
                short8_t afr = *(const short8_t*)(ktb + (size_t)(i0 + f * 16 + l15) * KD + kk * 32 + g * 8);
                sacc[f] = __builtin_amdgcn_mfma_f32_16x16x32_bf16(afr, kj[kk], sacc[f], 0, 0, 0);
            }
        }
        // transform: P = exp2(scale*(2*dot - sq_i - sq_j)); write P^T to LDS
#pragma unroll
        for (int f = 0; f < 4; f++) {
            shortx4 pk;
#pragma unroll
            for (int r = 0; r < 4; r++) {
                int ii = i0 + f * 16 + g * 4 + r;
                float p = exp2f((2.f * sacc[f][r] - sqb[ii] - sqj) * kScale);
                dsum += p;
                pk[r] = (short)f2bf(p);
            }
            *(shortx4*)&pt[wv][l15][f * 16 + g * 4] = pk;
        }
        __syncthreads();   // P^T writes visible before cross-lane reads
        // PV: acc[vd][j] += V[vd][i] * P[i][j]
#pragma unroll
        for (int k2 = 0; k2 < 2; k2++) {
            short8_t pfr = *(const short8_t*)&pt[wv][l15][k2 * 32 + g * 8];
#pragma unroll
            for (int m = 0; m < 16; m++) {
                short8_t vfr = *(const short8_t*)(vbb + (size_t)(m * 16 + l15) * Nn + i0 + k2 * 32 + g * 8);
                acc[m] = __builtin_amdgcn_mfma_f32_16x16x32_bf16(vfr, pfr, acc[m], 0, 0, 0);
            }
        }
        __syncthreads();   // protect pt against next-iteration overwrite (WAR)
    }

    // column sums: lanes {l15, l15+16, l15+32, l15+48} hold partials for col j
    dsum += __shfl_xor(dsum, 16, 64);
    dsum += __shfl_xor(dsum, 32, 64);
    float rden = 1.f / dsum;

    float* ob = out + ((size_t)(b * 512 + 256)) * Nn + j;
#pragma unroll
    for (int m = 0; m < 16; m++) {
#pragma unroll
        for (int r = 0; r < 4; r++) {
            int vd = m * 16 + g * 4 + r;
            ob[(size_t)vd * Nn] = acc[m][r] * rden;
        }
    }
}

// ---------------------------------------------------------------------------
extern "C" void kernel_launch(void* const* d_in, const int* in_sizes, int n_in,
                              void* d_out, int out_size, void* d_ws, size_t ws_size,
                              hipStream_t stream) {
    const float* x     = (const float*)d_in[0];
    const float* kw    = (const float*)d_in[1];
    const float* kbias = (const float*)d_in[2];
    const float* vw    = (const float*)d_in[3];
    const float* vbias = (const float*)d_in[4];
    float* out = (float*)d_out;  // reference output dtype is FLOAT32
    char* ws = (char*)d_ws;

    // workspace layout (bytes) — total 44,908,544
    constexpr size_t XPAD = 0;                         // 8*66*66*256*2 = 17,842,176
    constexpr size_t WTK  = 17842176;                  // 9*128*256*2   =    589,824
    constexpr size_t WTV  = 18432000;                  // 9*256*256*2   =  1,179,648
    constexpr size_t KT   = 19611648;                  // 8*4096*128*2  =  8,388,608
    constexpr size_t VB   = 28000256;                  // 8*256*4096*2  = 16,777,216
    constexpr size_t SQ   = 44777472;                  // 8*4096*4      =    131,072

    ushort* xpad = (ushort*)(ws + XPAD);
    ushort* wtk  = (ushort*)(ws + WTK);
    ushort* wtv  = (ushort*)(ws + WTV);
    ushort* ktw  = (ushort*)(ws + KT);
    ushort* vbw  = (ushort*)(ws + VB);
    float*  sqw  = (float*)(ws + SQ);

    hipMemsetAsync(xpad, 0, 17842176, stream);  // zero borders of padded input
    pad_transpose<<<dim3(64, Bb, 4), 256, 0, stream>>>(x, xpad);
    repack_w<<<dim3(384), 256, 0, stream>>>(kw, vw, wtk, wtv);
    conv_gemm<0, KD><<<dim3(64, Bb, 1), 256, 0, stream>>>(xpad, wtk, kbias, ktw, nullptr, nullptr);
    conv_gemm<1, VD><<<dim3(64, Bb, 2), 256, 0, stream>>>(xpad, wtv, vbias, nullptr, out, vbw);
    sq_kernel<<<dim3(128), 256, 0, stream>>>(ktw, sqw);
    attn_kernel<<<dim3(64, Bb), 256, 0, stream>>>(ktw, vbw, sqw, out);
}

// Round 5
// 614.494 us; speedup vs baseline: 1.9647x; 1.9647x over previous
//
#include <hip/hip_runtime.h>
#include <hip/hip_bf16.h>
#include <cstdint>

// Problem constants
constexpr int Bb = 8, Cc = 256, Hh = 64, Ww = 64, Nn = 4096;
constexpr int KD = 128, VD = 256, HP = 66; // HP = padded spatial (64+2)

typedef __attribute__((ext_vector_type(8))) short short8_t;   // 8 bf16 (4 VGPR) MFMA frag
typedef __attribute__((ext_vector_type(4))) short shortx4;    // 4 bf16 packed store
typedef __attribute__((ext_vector_type(4))) float floatx4;    // MFMA accumulator

static __device__ __forceinline__ ushort f2bf(float f) {
    union { float f; uint32_t u; } v{f};
    uint32_t r = v.u + 0x7FFFu + ((v.u >> 16) & 1u);  // RNE
    return (ushort)(r >> 16);
}
static __device__ __forceinline__ float bf2f(ushort b) {
    union { uint32_t u; float f; } v{(uint32_t)b << 16};
    return v.f;
}

// async global->LDS, 16B per lane; lds base must be wave-uniform (HW adds lane*16)
static __device__ __forceinline__ void gload_lds16(const void* g, void* l) {
    __builtin_amdgcn_global_load_lds((const __attribute__((address_space(1))) uint32_t*)g,
                                     (__attribute__((address_space(3))) uint32_t*)l, 16, 0, 0);
}

// ---------------------------------------------------------------------------
// K1: x[b][c][y][x] (f32) -> xpad[b][y+1][x+1][c] (bf16, channel-last).
// 1-D grid, b = bid&7 so batch b stays on XCD b (round-robin dispatch).
__global__ __launch_bounds__(256) void pad_transpose(const float* __restrict__ x,
                                                     ushort* __restrict__ xpad) {
    int bid = blockIdx.x;
    int b = bid & 7, rest = bid >> 3;
    int y = rest & 63, cg = rest >> 6;   // cg: 64-channel group
    int t = threadIdx.x;
    __shared__ float tile[64][65];
    int xcol = t & 63;
    int crow = t >> 6;  // 0..3
    const float* xb = x + ((size_t)(b * Cc + cg * 64) * Nn) + y * 64;
#pragma unroll
    for (int i = 0; i < 16; i++) {
        int c = crow + i * 4;
        tile[c][xcol] = xb[(size_t)c * Nn + xcol];
    }
    __syncthreads();
    int c = t & 63;
    int x4 = t >> 6;
    ushort* dst = xpad + (((size_t)(b * HP + (y + 1)) * HP) + 1) * Cc + cg * 64 + c;
#pragma unroll
    for (int i = 0; i < 16; i++) {
        int xx = x4 + i * 4;
        dst[(size_t)xx * Cc] = f2bf(tile[c][xx]);
    }
}

// ---------------------------------------------------------------------------
// K2: repack weights w[oc][c][3][3] (f32) -> wt[r][oc][c] (bf16), r = dy*3+dx
__global__ __launch_bounds__(256) void repack_w(const float* __restrict__ kw,
                                                const float* __restrict__ vw,
                                                ushort* __restrict__ wtk,
                                                ushort* __restrict__ wtv) {
    int idx = blockIdx.x * 256 + threadIdx.x;
    const int nk = KD * Cc;   // 32768
    const int nv = VD * Cc;   // 65536
    if (idx < nk) {
        const float* src = kw + (size_t)idx * 9;
        int oc = idx / Cc, c = idx % Cc;
#pragma unroll
        for (int r = 0; r < 9; r++) wtk[((size_t)r * KD + oc) * Cc + c] = f2bf(src[r]);
    } else if (idx < nk + nv) {
        int j = idx - nk;
        const float* src = vw + (size_t)j * 9;
        int oc = j / Cc, c = j % Cc;
#pragma unroll
        for (int r = 0; r < 9; r++) wtv[((size_t)r * VD + oc) * Cc + c] = f2bf(src[r]);
    }
}

// ---------------------------------------------------------------------------
// K3: implicit-GEMM conv3x3 via MFMA. Block = 4 waves, M_tile=128 oc,
// N_tile=64 (one image row), K = 9 taps x 256 ch. 1-D grid, b = bid&7.
// MODE 0: key conv -> Kt[b][pos][oc] bf16 (+bias).
// MODE 1: val conv -> d_out ch 0..255 as FLOAT32 (+bias) and Vb bf16 copy.
template <int MODE, int OC>
__global__ __launch_bounds__(256) void conv_gemm(const ushort* __restrict__ xpad,
                                                 const ushort* __restrict__ wt,
                                                 const float* __restrict__ bias,
                                                 ushort* __restrict__ kt_out,
                                                 float* __restrict__ f32_out,
                                                 ushort* __restrict__ vb_out) {
    int bid = blockIdx.x;
    int b = bid & 7;
    int ocg, y;
    if (OC == 128) { ocg = 0; y = bid >> 3; }
    else           { ocg = (bid >> 3) & 1; y = bid >> 4; }
    int lane = threadIdx.x & 63, wv = threadIdx.x >> 6;
    int l15 = lane & 15, g = lane >> 4;
    int oc0 = ocg * 128;

    floatx4 acc[8];
#pragma unroll
    for (int m = 0; m < 8; m++) acc[m] = (floatx4){0.f, 0.f, 0.f, 0.f};

    const ushort* xb = xpad + ((size_t)b * HP * HP) * Cc;
    int xcol = wv * 16 + l15;  // output x position (wave's 16 columns)

#pragma unroll 1
    for (int r = 0; r < 9; r++) {
        int dy = r / 3, dx = r % 3;
        const ushort* bsrc = xb + ((size_t)(y + dy) * HP + xcol + dx) * Cc + g * 8;
        const ushort* asrc = wt + ((size_t)r * OC + oc0 + l15) * Cc + g * 8;
#pragma unroll
        for (int cc = 0; cc < 8; cc++) {  // 8 k-steps of 32 channels
            short8_t bfrag = *(const short8_t*)(bsrc + cc * 32);
#pragma unroll
            for (int m = 0; m < 8; m++) {
                short8_t afrag = *(const short8_t*)(asrc + (size_t)m * 16 * Cc + cc * 32);
                acc[m] = __builtin_amdgcn_mfma_f32_16x16x32_bf16(afrag, bfrag, acc[m], 0, 0, 0);
            }
        }
    }

    int pos = y * 64 + xcol;
    if (MODE == 0) {
        // Kt[b][pos][oc]; D rows (oc) = m*16 + g*4 + reg -> 4 consecutive, pack 8B
        ushort* kt = kt_out + ((size_t)(b * Nn + pos)) * KD;
#pragma unroll
        for (int m = 0; m < 8; m++) {
            floatx4 bv = *(const floatx4*)(bias + m * 16 + g * 4);
            shortx4 pk;
#pragma unroll
            for (int r = 0; r < 4; r++) pk[r] = (short)f2bf(acc[m][r] + bv[r]);
            *(shortx4*)(kt + m * 16 + g * 4) = pk;
        }
    } else {
#pragma unroll
        for (int m = 0; m < 8; m++) {
            floatx4 bv = *(const floatx4*)(bias + oc0 + m * 16 + g * 4);
#pragma unroll
            for (int r = 0; r < 4; r++) {
                int oc = oc0 + m * 16 + g * 4 + r;
                float v = acc[m][r] + bv[r];
                f32_out[((size_t)(b * 512 + oc)) * Nn + pos] = v;       // d_out f32
                vb_out[((size_t)(b * VD + oc)) * Nn + pos] = f2bf(v);   // bf16 for PV MFMA
            }
        }
    }
}

// ---------------------------------------------------------------------------
// K4: sq[b*N+pos] = sum_ch Kt[pos][ch]^2 (f32). XCD-local: b = bid&7.
__global__ __launch_bounds__(256) void sq_kernel(const ushort* __restrict__ kt,
                                                 float* __restrict__ sq) {
    int bid = blockIdx.x;
    int idx = (bid & 7) * Nn + (bid >> 3) * 256 + threadIdx.x;
    const ushort* src = kt + (size_t)idx * KD;
    float s = 0.f;
#pragma unroll
    for (int i = 0; i < 16; i++) {
        short8_t v = *(const short8_t*)(src + i * 8);
#pragma unroll
        for (int e = 0; e < 8; e++) {
            float f = bf2f((ushort)v[e]);
            s += f * f;
        }
    }
    sq[idx] = s;
}

// ---------------------------------------------------------------------------
// K5: fused attention, LDS-staged tiles (single-buffered K and V, 57.25 KB).
// Block = 4 waves x 16 j-cols = 64 cols. b = bid&7 -> batch pinned to one XCD
// so Kt+V (3MB) are L2-resident. Per i-tile (64 rows):
//   schedule: S(reads bufK) -> P-write -> sync1 -> issue K(it+1) ->
//             PV(reads pt+bufV) -> sync2 (drains K prefetch) -> issue V(it+1)
// K tile 64x128 bf16 (16KB, 4 gload/wave), V tile 256x64 bf16 (32KB, 8/wave).
// Source-side XOR swizzle (16B-unit ^= row&7); read slot = unit ^ (l15&7).
__global__ __launch_bounds__(256) void attn_kernel(const ushort* __restrict__ kt,
                                                   const ushort* __restrict__ vb,
                                                   const float* __restrict__ sq,
                                                   float* __restrict__ out) {
    int bid = blockIdx.x;
    int b = bid & 7, jt = bid >> 3;
    int lane = threadIdx.x & 63, wv = threadIdx.x >> 6;
    int l15 = lane & 15, g = lane >> 4;

    __shared__ ushort bufK[64 * 128];      // 16KB: [row][swizzled 16B units]
    __shared__ ushort bufV[256 * 64];      // 32KB: [vd][swizzled 16B units]
    __shared__ ushort pt[4][16][72];       // 9KB: per-wave P^T tile [j][i]

    int j = jt * 64 + wv * 16 + l15;
    const ushort* ktb = kt + ((size_t)b * Nn) * KD;
    const ushort* vbb = vb + ((size_t)b * VD) * Nn;
    const float* sqb = sq + b * Nn;

    // per-lane staging source pointers (it=0); LDS dests are wave-uniform
    const ushort* skp[4];
#pragma unroll
    for (int h = 0; h < 4; h++) {
        int row = wv * 16 + h * 4 + (lane >> 4);
        skp[h] = ktb + (size_t)row * KD + (((lane & 15) ^ (row & 7)) * 8);
    }
    const ushort* svp[8];
#pragma unroll
    for (int h = 0; h < 8; h++) {
        int vd = wv * 64 + h * 8 + (lane >> 3);
        svp[h] = vbb + (size_t)vd * Nn + (((lane & 7) ^ (vd & 7)) * 8);
    }

    float sqj = sqb[j];
    short8_t kj[4];
#pragma unroll
    for (int kk = 0; kk < 4; kk++)
        kj[kk] = *(const short8_t*)(ktb + (size_t)j * KD + kk * 32 + g * 8);

    floatx4 acc[16];
#pragma unroll
    for (int m = 0; m < 16; m++) acc[m] = (floatx4){0.f, 0.f, 0.f, 0.f};
    float dsum = 0.f;
    constexpr float kScale = 0.08838834764831845f * 1.4426950408889634f;  // log2e/sqrt(128)
    const int swzA = l15 & 7;

    // prologue: stage K(0), V(0)
#pragma unroll
    for (int h = 0; h < 4; h++) gload_lds16(skp[h], &bufK[(wv * 16 + h * 4) * 128]);
#pragma unroll
    for (int h = 0; h < 8; h++) gload_lds16(svp[h], &bufV[(wv * 64 + h * 8) * 64]);
    __syncthreads();   // implicit vmcnt(0): both tiles resident

#pragma unroll 1
    for (int it = 0; it < 64; ++it) {
        int i0 = it * 64;

        // S-phase: A-frags from LDS K tile
        floatx4 sacc[4];
#pragma unroll
        for (int f = 0; f < 4; f++) sacc[f] = (floatx4){0.f, 0.f, 0.f, 0.f};
#pragma unroll
        for (int kk = 0; kk < 4; kk++) {
#pragma unroll
            for (int f = 0; f < 4; f++) {
                short8_t afr = *(const short8_t*)&bufK[(f * 16 + l15) * 128 + ((kk * 4 + g) ^ swzA) * 8];
                sacc[f] = __builtin_amdgcn_mfma_f32_16x16x32_bf16(afr, kj[kk], sacc[f], 0, 0, 0);
            }
        }
        // P = exp2(scale*(2*dot - sq_i - sq_j)); write P^T to per-wave LDS
#pragma unroll
        for (int f = 0; f < 4; f++) {
            shortx4 pk;
#pragma unroll
            for (int r = 0; r < 4; r++) {
                int ii = i0 + f * 16 + g * 4 + r;
                float p = exp2f((2.f * sacc[f][r] - sqb[ii] - sqj) * kScale);
                dsum += p;
                pk[r] = (short)f2bf(p);
            }
            *(shortx4*)&pt[wv][l15][f * 16 + g * 4] = pk;
        }
        __syncthreads();   // sync1: pt visible; all waves done reading bufK

        // issue K(it+1) prefetch (WAR-safe; drained by sync2's implicit vmcnt0)
        if (it < 63) {
#pragma unroll
            for (int h = 0; h < 4; h++)
                gload_lds16(skp[h] + (size_t)(i0 + 64) * KD, &bufK[(wv * 16 + h * 4) * 128]);
        }

        // PV: acc[vd][j] += V[vd][i] * P[i][j]
#pragma unroll
        for (int k2 = 0; k2 < 2; k2++) {
            short8_t pfr = *(const short8_t*)&pt[wv][l15][k2 * 32 + g * 8];
#pragma unroll
            for (int m = 0; m < 16; m++) {
                short8_t vfr = *(const short8_t*)&bufV[(m * 16 + l15) * 64 + ((k2 * 4 + g) ^ swzA) * 8];
                acc[m] = __builtin_amdgcn_mfma_f32_16x16x32_bf16(vfr, pfr, acc[m], 0, 0, 0);
            }
        }
        __syncthreads();   // sync2: bufV reads done; K prefetch drained; pt WAR

        // issue V(it+1) prefetch (drained at next iter's sync1)
        if (it < 63) {
#pragma unroll
            for (int h = 0; h < 8; h++)
                gload_lds16(svp[h] + (i0 + 64), &bufV[(wv * 64 + h * 8) * 64]);
        }
    }

    // column sums: lanes {l15, l15+16, l15+32, l15+48} hold partials for col j
    dsum += __shfl_xor(dsum, 16, 64);
    dsum += __shfl_xor(dsum, 32, 64);
    float rden = 1.f / dsum;

    float* ob = out + ((size_t)(b * 512 + 256)) * Nn + j;
#pragma unroll
    for (int m = 0; m < 16; m++) {
#pragma unroll
        for (int r = 0; r < 4; r++) {
            int vd = m * 16 + g * 4 + r;
            ob[(size_t)vd * Nn] = acc[m][r] * rden;
        }
    }
}

// ---------------------------------------------------------------------------
extern "C" void kernel_launch(void* const* d_in, const int* in_sizes, int n_in,
                              void* d_out, int out_size, void* d_ws, size_t ws_size,
                              hipStream_t stream) {
    const float* x     = (const float*)d_in[0];
    const float* kw    = (const float*)d_in[1];
    const float* kbias = (const float*)d_in[2];
    const float* vw    = (const float*)d_in[3];
    const float* vbias = (const float*)d_in[4];
    float* out = (float*)d_out;  // reference output dtype is FLOAT32
    char* ws = (char*)d_ws;

    // workspace layout (bytes) — total 44,908,544
    constexpr size_t XPAD = 0;                         // 8*66*66*256*2 = 17,842,176
    constexpr size_t WTK  = 17842176;                  // 9*128*256*2   =    589,824
    constexpr size_t WTV  = 18432000;                  // 9*256*256*2   =  1,179,648
    constexpr size_t KT   = 19611648;                  // 8*4096*128*2  =  8,388,608
    constexpr size_t VB   = 28000256;                  // 8*256*4096*2  = 16,777,216
    constexpr size_t SQ   = 44777472;                  // 8*4096*4      =    131,072

    ushort* xpad = (ushort*)(ws + XPAD);
    ushort* wtk  = (ushort*)(ws + WTK);
    ushort* wtv  = (ushort*)(ws + WTV);
    ushort* ktw  = (ushort*)(ws + KT);
    ushort* vbw  = (ushort*)(ws + VB);
    float*  sqw  = (float*)(ws + SQ);

    hipMemsetAsync(xpad, 0, 17842176, stream);  // zero borders of padded input
    pad_transpose<<<dim3(2048), 256, 0, stream>>>(x, xpad);
    repack_w<<<dim3(384), 256, 0, stream>>>(kw, vw, wtk, wtv);
    conv_gemm<0, KD><<<dim3(512), 256, 0, stream>>>(xpad, wtk, kbias, ktw, nullptr, nullptr);
    conv_gemm<1, VD><<<dim3(1024), 256, 0, stream>>>(xpad, wtv, vbias, nullptr, out, vbw);
    sq_kernel<<<dim3(128), 256, 0, stream>>>(ktw, sqw);
    attn_kernel<<<dim3(512), 256, 0, stream>>>(ktw, vbw, sqw, out);
}

// Round 6
// 277.113 us; speedup vs baseline: 4.3568x; 2.2175x over previous
//
#include <hip/hip_runtime.h>
#include <hip/hip_bf16.h>
#include <cstdint>

// Problem constants
constexpr int Bb = 8, Cc = 256, Hh = 64, Ww = 64, Nn = 4096;
constexpr int KD = 128, VD = 256, HP = 66; // HP = padded spatial (64+2)

typedef __attribute__((ext_vector_type(8))) short short8_t;   // 8 bf16 (4 VGPR) MFMA frag
typedef __attribute__((ext_vector_type(4))) short shortx4;    // 4 bf16 packed store
typedef __attribute__((ext_vector_type(4))) float floatx4;    // MFMA accumulator

static __device__ __forceinline__ ushort f2bf(float f) {
    union { float f; uint32_t u; } v{f};
    uint32_t r = v.u + 0x7FFFu + ((v.u >> 16) & 1u);  // RNE
    return (ushort)(r >> 16);
}
static __device__ __forceinline__ float bf2f(ushort b) {
    union { uint32_t u; float f; } v{(uint32_t)b << 16};
    return v.f;
}

// async global->LDS, 16B per lane; lds base must be wave-uniform (HW adds lane*16)
static __device__ __forceinline__ void gload_lds16(const void* g, void* l) {
    __builtin_amdgcn_global_load_lds((const __attribute__((address_space(1))) uint32_t*)g,
                                     (__attribute__((address_space(3))) uint32_t*)l, 16, 0, 0);
}

// ---------------------------------------------------------------------------
// K1: x[b][c][y][x] (f32) -> xpad[b][y+1][x+1][c] (bf16, channel-last).
// 1-D grid, b = bid&7 so batch b stays on XCD b (round-robin dispatch).
__global__ __launch_bounds__(256) void pad_transpose(const float* __restrict__ x,
                                                     ushort* __restrict__ xpad) {
    int bid = blockIdx.x;
    int b = bid & 7, rest = bid >> 3;
    int y = rest & 63, cg = rest >> 6;   // cg: 64-channel group
    int t = threadIdx.x;
    __shared__ float tile[64][65];
    int xcol = t & 63;
    int crow = t >> 6;  // 0..3
    const float* xb = x + ((size_t)(b * Cc + cg * 64) * Nn) + y * 64;
#pragma unroll
    for (int i = 0; i < 16; i++) {
        int c = crow + i * 4;
        tile[c][xcol] = xb[(size_t)c * Nn + xcol];
    }
    __syncthreads();
    int c = t & 63;
    int x4 = t >> 6;
    ushort* dst = xpad + (((size_t)(b * HP + (y + 1)) * HP) + 1) * Cc + cg * 64 + c;
#pragma unroll
    for (int i = 0; i < 16; i++) {
        int xx = x4 + i * 4;
        dst[(size_t)xx * Cc] = f2bf(tile[c][xx]);
    }
}

// ---------------------------------------------------------------------------
// K2: repack weights w[oc][c][3][3] (f32) -> wt[r][oc][c] (bf16), r = dy*3+dx
__global__ __launch_bounds__(256) void repack_w(const float* __restrict__ kw,
                                                const float* __restrict__ vw,
                                                ushort* __restrict__ wtk,
                                                ushort* __restrict__ wtv) {
    int idx = blockIdx.x * 256 + threadIdx.x;
    const int nk = KD * Cc;   // 32768
    const int nv = VD * Cc;   // 65536
    if (idx < nk) {
        const float* src = kw + (size_t)idx * 9;
        int oc = idx / Cc, c = idx % Cc;
#pragma unroll
        for (int r = 0; r < 9; r++) wtk[((size_t)r * KD + oc) * Cc + c] = f2bf(src[r]);
    } else if (idx < nk + nv) {
        int j = idx - nk;
        const float* src = vw + (size_t)j * 9;
        int oc = j / Cc, c = j % Cc;
#pragma unroll
        for (int r = 0; r < 9; r++) wtv[((size_t)r * VD + oc) * Cc + c] = f2bf(src[r]);
    }
}

// ---------------------------------------------------------------------------
// K3: implicit-GEMM conv3x3 via MFMA, weight slab LDS-staged.
// Block = 4 waves, M_tile=128 oc, N_tile=64 (one image row), K = 9 taps x 256ch
// processed as 18 half-slabs (tap r, ch-half hc) of 128oc x 128ch = 32KB,
// double-buffered via global_load_lds with source-side XOR swizzle
// (16B-unit ^= row&7) so ds_read_b128 A-frags are bank-conflict-free.
// All 4 waves share the staged weights (kills the prior 4x redundant global
// traffic that made this kernel latency-bound at 5% MfmaUtil).
// MODE 0: key conv -> Kt[b][pos][oc] bf16 (+bias).
// MODE 1: val conv -> d_out ch 0..255 as FLOAT32 (+bias) and Vb bf16 copy.
template <int MODE, int OC>
__global__ __launch_bounds__(256) void conv_gemm(const ushort* __restrict__ xpad,
                                                 const ushort* __restrict__ wt,
                                                 const float* __restrict__ bias,
                                                 ushort* __restrict__ kt_out,
                                                 float* __restrict__ f32_out,
                                                 ushort* __restrict__ vb_out) {
    int bid = blockIdx.x;
    int b = bid & 7;
    int ocg, y;
    if (OC == 128) { ocg = 0; y = bid >> 3; }
    else           { ocg = (bid >> 3) & 1; y = bid >> 4; }
    int lane = threadIdx.x & 63, wv = threadIdx.x >> 6;
    int l15 = lane & 15, g = lane >> 4;
    int oc0 = ocg * 128;
    const int swzA = l15 & 7;

    __shared__ ushort wslab[2][128 * 128];   // 2 x 32KB weight half-slabs

    // per-lane staging source offsets (elements) within a half-slab
    size_t wsoff[8];
    int ldsrow[8];
#pragma unroll
    for (int h = 0; h < 8; h++) {
        int row = wv * 32 + h * 4 + (lane >> 4);      // oc row this lane stages
        wsoff[h] = (size_t)row * Cc + (((lane & 15) ^ (row & 7)) * 8);
        ldsrow[h] = (wv * 32 + h * 4) * 128;
    }

    floatx4 acc[8];
#pragma unroll
    for (int m = 0; m < 8; m++) acc[m] = (floatx4){0.f, 0.f, 0.f, 0.f};

    const ushort* xb = xpad + ((size_t)b * HP * HP) * Cc;
    int xcol = wv * 16 + l15;  // output x position (wave's 16 columns)

    // stage half-slab hs=(r,hc) into wslab[bi]
    auto stage = [&](int hs, int bi) {
        int r = hs >> 1, hc = hs & 1;
        const ushort* wb = wt + ((size_t)r * OC + oc0) * Cc + hc * 128;
#pragma unroll
        for (int h = 0; h < 8; h++)
            gload_lds16(wb + wsoff[h], &wslab[bi][ldsrow[h]]);
    };

    stage(0, 0);
    __syncthreads();   // implicit vmcnt(0): slab 0 resident

#pragma unroll 1
    for (int hs = 0; hs < 18; ++hs) {
        int bi = hs & 1;
        if (hs < 17) stage(hs + 1, bi ^ 1);   // prefetch; drained by end barrier

        int r = hs >> 1, hc = hs & 1;
        int dy = r / 3, dx = r % 3;
        const ushort* bsrc = xb + ((size_t)(y + dy) * HP + xcol + dx) * Cc + hc * 128 + g * 8;
#pragma unroll
        for (int cc = 0; cc < 4; cc++) {      // 4 k-steps of 32 channels
            short8_t bfrag = *(const short8_t*)(bsrc + cc * 32);
#pragma unroll
            for (int m = 0; m < 8; m++) {
                short8_t afrag = *(const short8_t*)&wslab[bi][(m * 16 + l15) * 128 + ((cc * 4 + g) ^ swzA) * 8];
                acc[m] = __builtin_amdgcn_mfma_f32_16x16x32_bf16(afrag, bfrag, acc[m], 0, 0, 0);
            }
        }
        __syncthreads();   // reads done + prefetch drained
    }

    int pos = y * 64 + xcol;
    if (MODE == 0) {
        // Kt[b][pos][oc]; D rows (oc) = m*16 + g*4 + reg -> 4 consecutive, pack 8B
        ushort* kt = kt_out + ((size_t)(b * Nn + pos)) * KD;
#pragma unroll
        for (int m = 0; m < 8; m++) {
            floatx4 bv = *(const floatx4*)(bias + m * 16 + g * 4);
            shortx4 pk;
#pragma unroll
            for (int r = 0; r < 4; r++) pk[r] = (short)f2bf(acc[m][r] + bv[r]);
            *(shortx4*)(kt + m * 16 + g * 4) = pk;
        }
    } else {
#pragma unroll
        for (int m = 0; m < 8; m++) {
            floatx4 bv = *(const floatx4*)(bias + oc0 + m * 16 + g * 4);
#pragma unroll
            for (int r = 0; r < 4; r++) {
                int oc = oc0 + m * 16 + g * 4 + r;
                float v = acc[m][r] + bv[r];
                f32_out[((size_t)(b * 512 + oc)) * Nn + pos] = v;       // d_out f32
                vb_out[((size_t)(b * VD + oc)) * Nn + pos] = f2bf(v);   // bf16 for PV MFMA
            }
        }
    }
}

// ---------------------------------------------------------------------------
// K4: sq[b*N+pos] = sum_ch Kt[pos][ch]^2 (f32). XCD-local: b = bid&7.
__global__ __launch_bounds__(256) void sq_kernel(const ushort* __restrict__ kt,
                                                 float* __restrict__ sq) {
    int bid = blockIdx.x;
    int idx = (bid & 7) * Nn + (bid >> 3) * 256 + threadIdx.x;
    const ushort* src = kt + (size_t)idx * KD;
    float s = 0.f;
#pragma unroll
    for (int i = 0; i < 16; i++) {
        short8_t v = *(const short8_t*)(src + i * 8);
#pragma unroll
        for (int e = 0; e < 8; e++) {
            float f = bf2f((ushort)v[e]);
            s += f * f;
        }
    }
    sq[idx] = s;
}

// ---------------------------------------------------------------------------
// K5: fused attention, LDS-staged tiles (single-buffered K and V, 57.25 KB).
// Block = 4 waves x 16 j-cols = 64 cols. b = bid&7 -> batch pinned to one XCD
// so Kt+V (3MB) are L2-resident. Per i-tile (64 rows):
//   schedule: S(reads bufK) -> P-write -> sync1 -> issue K(it+1) ->
//             PV(reads pt+bufV) -> sync2 (drains K prefetch) -> issue V(it+1)
// K tile 64x128 bf16 (16KB, 4 gload/wave), V tile 256x64 bf16 (32KB, 8/wave).
// Source-side XOR swizzle (16B-unit ^= row&7); read slot = unit ^ (l15&7).
__global__ __launch_bounds__(256) void attn_kernel(const ushort* __restrict__ kt,
                                                   const ushort* __restrict__ vb,
                                                   const float* __restrict__ sq,
                                                   float* __restrict__ out) {
    int bid = blockIdx.x;
    int b = bid & 7, jt = bid >> 3;
    int lane = threadIdx.x & 63, wv = threadIdx.x >> 6;
    int l15 = lane & 15, g = lane >> 4;

    __shared__ ushort bufK[64 * 128];      // 16KB: [row][swizzled 16B units]
    __shared__ ushort bufV[256 * 64];      // 32KB: [vd][swizzled 16B units]
    __shared__ ushort pt[4][16][72];       // 9KB: per-wave P^T tile [j][i]

    int j = jt * 64 + wv * 16 + l15;
    const ushort* ktb = kt + ((size_t)b * Nn) * KD;
    const ushort* vbb = vb + ((size_t)b * VD) * Nn;
    const float* sqb = sq + b * Nn;

    // per-lane staging source pointers (it=0); LDS dests are wave-uniform
    const ushort* skp[4];
#pragma unroll
    for (int h = 0; h < 4; h++) {
        int row = wv * 16 + h * 4 + (lane >> 4);
        skp[h] = ktb + (size_t)row * KD + (((lane & 15) ^ (row & 7)) * 8);
    }
    const ushort* svp[8];
#pragma unroll
    for (int h = 0; h < 8; h++) {
        int vd = wv * 64 + h * 8 + (lane >> 3);
        svp[h] = vbb + (size_t)vd * Nn + (((lane & 7) ^ (vd & 7)) * 8);
    }

    float sqj = sqb[j];
    short8_t kj[4];
#pragma unroll
    for (int kk = 0; kk < 4; kk++)
        kj[kk] = *(const short8_t*)(ktb + (size_t)j * KD + kk * 32 + g * 8);

    floatx4 acc[16];
#pragma unroll
    for (int m = 0; m < 16; m++) acc[m] = (floatx4){0.f, 0.f, 0.f, 0.f};
    float dsum = 0.f;
    constexpr float kScale = 0.08838834764831845f * 1.4426950408889634f;  // log2e/sqrt(128)
    const int swzA = l15 & 7;

    // prologue: stage K(0), V(0)
#pragma unroll
    for (int h = 0; h < 4; h++) gload_lds16(skp[h], &bufK[(wv * 16 + h * 4) * 128]);
#pragma unroll
    for (int h = 0; h < 8; h++) gload_lds16(svp[h], &bufV[(wv * 64 + h * 8) * 64]);
    __syncthreads();   // implicit vmcnt(0): both tiles resident

#pragma unroll 1
    for (int it = 0; it < 64; ++it) {
        int i0 = it * 64;

        // S-phase: A-frags from LDS K tile
        floatx4 sacc[4];
#pragma unroll
        for (int f = 0; f < 4; f++) sacc[f] = (floatx4){0.f, 0.f, 0.f, 0.f};
#pragma unroll
        for (int kk = 0; kk < 4; kk++) {
#pragma unroll
            for (int f = 0; f < 4; f++) {
                short8_t afr = *(const short8_t*)&bufK[(f * 16 + l15) * 128 + ((kk * 4 + g) ^ swzA) * 8];
                sacc[f] = __builtin_amdgcn_mfma_f32_16x16x32_bf16(afr, kj[kk], sacc[f], 0, 0, 0);
            }
        }
        // P = exp2(scale*(2*dot - sq_i - sq_j)); write P^T to per-wave LDS
#pragma unroll
        for (int f = 0; f < 4; f++) {
            shortx4 pk;
#pragma unroll
            for (int r = 0; r < 4; r++) {
                int ii = i0 + f * 16 + g * 4 + r;
                float p = exp2f((2.f * sacc[f][r] - sqb[ii] - sqj) * kScale);
                dsum += p;
                pk[r] = (short)f2bf(p);
            }
            *(shortx4*)&pt[wv][l15][f * 16 + g * 4] = pk;
        }
        __syncthreads();   // sync1: pt visible; all waves done reading bufK

        // issue K(it+1) prefetch (WAR-safe; drained by sync2's implicit vmcnt0)
        if (it < 63) {
#pragma unroll
            for (int h = 0; h < 4; h++)
                gload_lds16(skp[h] + (size_t)(i0 + 64) * KD, &bufK[(wv * 16 + h * 4) * 128]);
        }

        // PV: acc[vd][j] += V[vd][i] * P[i][j]
#pragma unroll
        for (int k2 = 0; k2 < 2; k2++) {
            short8_t pfr = *(const short8_t*)&pt[wv][l15][k2 * 32 + g * 8];
#pragma unroll
            for (int m = 0; m < 16; m++) {
                short8_t vfr = *(const short8_t*)&bufV[(m * 16 + l15) * 64 + ((k2 * 4 + g) ^ swzA) * 8];
                acc[m] = __builtin_amdgcn_mfma_f32_16x16x32_bf16(vfr, pfr, acc[m], 0, 0, 0);
            }
        }
        __syncthreads();   // sync2: bufV reads done; K prefetch drained; pt WAR

        // issue V(it+1) prefetch (drained at next iter's sync1)
        if (it < 63) {
#pragma unroll
            for (int h = 0; h < 8; h++)
                gload_lds16(svp[h] + (i0 + 64), &bufV[(wv * 64 + h * 8) * 64]);
        }
    }

    // column sums: lanes {l15, l15+16, l15+32, l15+48} hold partials for col j
    dsum += __shfl_xor(dsum, 16, 64);
    dsum += __shfl_xor(dsum, 32, 64);
    float rden = 1.f / dsum;

    float* ob = out + ((size_t)(b * 512 + 256)) * Nn + j;
#pragma unroll
    for (int m = 0; m < 16; m++) {
#pragma unroll
        for (int r = 0; r < 4; r++) {
            int vd = m * 16 + g * 4 + r;
            ob[(size_t)vd * Nn] = acc[m][r] * rden;
        }
    }
}

// ---------------------------------------------------------------------------
extern "C" void kernel_launch(void* const* d_in, const int* in_sizes, int n_in,
                              void* d_out, int out_size, void* d_ws, size_t ws_size,
                              hipStream_t stream) {
    const float* x     = (const float*)d_in[0];
    const float* kw    = (const float*)d_in[1];
    const float* kbias = (const float*)d_in[2];
    const float* vw    = (const float*)d_in[3];
    const float* vbias = (const float*)d_in[4];
    float* out = (float*)d_out;  // reference output dtype is FLOAT32
    char* ws = (char*)d_ws;

    // workspace layout (bytes) — total 44,908,544
    constexpr size_t XPAD = 0;                         // 8*66*66*256*2 = 17,842,176
    constexpr size_t WTK  = 17842176;                  // 9*128*256*2   =    589,824
    constexpr size_t WTV  = 18432000;                  // 9*256*256*2   =  1,179,648
    constexpr size_t KT   = 19611648;                  // 8*4096*128*2  =  8,388,608
    constexpr size_t VB   = 28000256;                  // 8*256*4096*2  = 16,777,216
    constexpr size_t SQ   = 44777472;                  // 8*4096*4      =    131,072

    ushort* xpad = (ushort*)(ws + XPAD);
    ushort* wtk  = (ushort*)(ws + WTK);
    ushort* wtv  = (ushort*)(ws + WTV);
    ushort* ktw  = (ushort*)(ws + KT);
    ushort* vbw  = (ushort*)(ws + VB);
    float*  sqw  = (float*)(ws + SQ);

    hipMemsetAsync(xpad, 0, 17842176, stream);  // zero borders of padded input
    pad_transpose<<<dim3(2048), 256, 0, stream>>>(x, xpad);
    repack_w<<<dim3(384), 256, 0, stream>>>(kw, vw, wtk, wtv);
    conv_gemm<0, KD><<<dim3(512), 256, 0, stream>>>(xpad, wtk, kbias, ktw, nullptr, nullptr);
    conv_gemm<1, VD><<<dim3(1024), 256, 0, stream>>>(xpad, wtv, vbias, nullptr, out, vbw);
    sq_kernel<<<dim3(128), 256, 0, stream>>>(ktw, sqw);
    attn_kernel<<<dim3(512), 256, 0, stream>>>(ktw, vbw, sqw, out);
}